// Round 14
// baseline (75.516 us; speedup 1.0000x reference)
//
#include <hip/hip_runtime.h>

// FocalLoss (sigmoid focal, mean reduction) — R14.
//   cls_score: [N=4, C=19, H=512, W=512] float32  (76 MiB, streamed once)
//   label:     [N=4, H=512, W=512] int32          (4 MiB, re-read 19x, cache-hot)
//
// Ledger (measured):
//  - R2/R7/R9: last-block SERIAL-REDUCE tail collapses regalloc -> 100+ us.
//  - R8 table (-3us), R11 poly (-0.8us): work removal pays. R10/R12/R13
//    (MLP, occupancy, packed VALU): null. Partial ~16us, finalize+gap ~4us.
// R14 lever: remove the second dispatch with a MINIMAL tail — one float
// atomicAdd of the block sum (no partials loop, no counter, no 2nd reduce).
// d_out zeroed each call via 4-byte hipMemsetAsync node. Order-variation of
// the float adds is ~1e-9 abs (threshold 5.5e-3). Main body = R12 verbatim.

#define NC 19
#define IGNORE_INDEX 255
#define ALPHA 0.25f

typedef float f32x4 __attribute__((ext_vector_type(4)));
typedef int   i32x4 __attribute__((ext_vector_type(4)));

constexpr int NBATCH = 4;
constexpr int HW = 512 * 512;                       // 2^18
constexpr int NQ = NBATCH * NC * (HW / 4);          // 4,980,736 float4-quads
constexpr int BLOCK = 256;
constexpr int QPT = 4;                              // quads per thread
constexpr int GRID = NQ / (BLOCK * QPT);            // 4864, exact
constexpr int TT = GRID * BLOCK;                    // 1,245,184 (stride)
constexpr float INV_TOTAL = 1.0f / (float)(NBATCH * NC * HW);

// Chebyshev-interpolant (7 nodes) of log1p(exp(-u)) on u in [0,6],
// monomials of x = u/3 - 1. Max err ~3.5e-4 (<< 5.5e-3 threshold).
constexpr float A0 =  0.0485865f;
constexpr float A1 = -0.1402039f;
constexpr float A2 =  0.2024491f;
constexpr float A3 = -0.2005852f;
constexpr float A4 =  0.1182934f;
constexpr float A5 = -0.0048016f;
constexpr float A6 = -0.0214538f;

template <int NWAVE>
__device__ __forceinline__ float block_reduce(float v, float* smem) {
    #pragma unroll
    for (int off = 32; off > 0; off >>= 1)
        v += __shfl_down(v, off, 64);
    const int lane = threadIdx.x & 63;
    const int wid  = threadIdx.x >> 6;
    if (lane == 0) smem[wid] = v;
    __syncthreads();
    float s = 0.0f;
    if (threadIdx.x == 0) {
        #pragma unroll
        for (int i = 0; i < NWAVE; ++i) s += smem[i];
    }
    return s;  // valid in thread 0 only
}

__device__ __forceinline__ float quad_loss(const f32x4 v, const i32x4 l4,
                                           const int c) {
    float acc = 0.0f;
    #pragma unroll
    for (int j = 0; j < 4; ++j) {
        const float xv  = v[j];
        const int   lb  = l4[j];
        const bool  val = (lb >= 0) && (lb != IGNORE_INDEX);
        const bool  t   = (lb == c);

        // softplus q(|x|) via degree-6 polynomial, no LDS, no trans.
        const float u  = fminf(fabsf(xv), 6.0f);
        const float xx = fmaf(u, 0.33333333f, -1.0f);
        float sp = A6;
        sp = fmaf(sp, xx, A5);
        sp = fmaf(sp, xx, A4);
        sp = fmaf(sp, xx, A3);
        sp = fmaf(sp, xx, A2);
        sp = fmaf(sp, xx, A1);
        sp = fmaf(sp, xx, A0);

        const float y   = t ? -xv : xv;
        const float d   = y + (t ? 1.0f : 0.0f);    // t? 1-x : x
        const float w   = (val ? ALPHA : 0.0f) * d * d;
        const float bce = fmaxf(y, 0.0f) + sp;      // = max(x,0)-x*t+q(|x|)
        acc = fmaf(bce, w, acc);
    }
    return acc;
}

__global__ __launch_bounds__(BLOCK, 8) void focal_partial(
        const f32x4* __restrict__ x,
        const i32x4* __restrict__ lab4,
        float*       __restrict__ out) {
    const int tid = blockIdx.x * BLOCK + threadIdx.x;

    // Per-quad class ids / label indices (q_k = tid + k*TT, exact tiling).
    int c_[QPT];
    int li_[QPT];
    #pragma unroll
    for (int k = 0; k < QPT; ++k) {
        const int      q     = tid + k * TT;
        const unsigned plane = (unsigned)q >> 16;
        const unsigned n     = plane / NC;          // magic-mul div
        c_[k]  = (int)(plane - n * NC);
        li_[k] = (int)((n << 16) + (q & 65535));
    }

    // Issue all 8 loads back-to-back; pin live (R7/R9 serialization guard).
    f32x4 v0 = x[tid + 0 * TT], v1 = x[tid + 1 * TT],
          v2 = x[tid + 2 * TT], v3 = x[tid + 3 * TT];
    i32x4 l0 = lab4[li_[0]], l1 = lab4[li_[1]],
          l2 = lab4[li_[2]], l3 = lab4[li_[3]];
    asm volatile("" : "+v"(v0), "+v"(v1), "+v"(v2), "+v"(v3),
                      "+v"(l0), "+v"(l1), "+v"(l2), "+v"(l3));

    float acc = quad_loss(v0, l0, c_[0]);
    acc += quad_loss(v1, l1, c_[1]);
    acc += quad_loss(v2, l2, c_[2]);
    acc += quad_loss(v3, l3, c_[3]);

    __shared__ float smem[BLOCK / 64];
    const float s = block_reduce<BLOCK / 64>(acc, smem);

    // Minimal tail: one device-scope float atomicAdd of the scaled block sum.
    if (threadIdx.x == 0)
        atomicAdd(out, s * INV_TOTAL);              // LOSS_WEIGHT == 1.0
}

extern "C" void kernel_launch(void* const* d_in, const int* in_sizes, int n_in,
                              void* d_out, int out_size, void* d_ws, size_t ws_size,
                              hipStream_t stream) {
    const f32x4* cls_score = (const f32x4*)d_in[0];
    const i32x4* lab4      = (const i32x4*)d_in[1];
    float* out = (float*)d_out;

    hipMemsetAsync(out, 0, sizeof(float), stream);
    focal_partial<<<GRID, BLOCK, 0, stream>>>(cls_score, lab4, out);
}

// Round 15
// 20.691 us; speedup vs baseline: 3.6497x; 3.6497x over previous
//
#include <hip/hip_runtime.h>

// FocalLoss (sigmoid focal, mean reduction) — R15.
//   cls_score: [N=4, C=19, H=512, W=512] float32  (76 MiB, streamed once)
//   label:     [N=4, H=512, W=512] int32          (4 MiB, read ONCE)
//
// Ledger (measured, corrected):
//  - Fused tails die from same-address device-atomic serialization
//    (11-44 ns/op x GRID), NOT regalloc: R2/R7/R9/R14 deltas all fit.
//    => two-kernel structure is forced at GRID >= ~1000.
//  - Work removal pays ~1:1 (trans -3us R8; LDS -0.8us R11). Structure
//    levers (MLP R10, occupancy R12, packed VALU R13) are null.
// R15 lever: remove label re-reads + index math. One pixel-quad per thread:
// label quad loaded ONCE, valid-mask computed ONCE, then 19 independent
// channel loads (16B each, plane stride) fully unrolled — acc is the only
// dependence, so the compiler can run loads arbitrarily deep.

#define NC 19
#define IGNORE_INDEX 255
#define ALPHA 0.25f

typedef float f32x4 __attribute__((ext_vector_type(4)));
typedef int   i32x4 __attribute__((ext_vector_type(4)));

constexpr int NBATCH = 4;
constexpr int HW = 512 * 512;                       // 2^18
constexpr int QPP = HW / 4;                         // 65536 pixel-quads/plane
constexpr int NP = NBATCH * QPP;                    // 262,144 pixel-quads
constexpr int BLOCK = 256;
constexpr int GRID = NP / BLOCK;                    // 1024, exact
constexpr int BLOCK2 = 1024;
constexpr float INV_TOTAL = 1.0f / (float)(NBATCH * NC * HW);

// Chebyshev-interpolant (7 nodes) of log1p(exp(-u)) on u in [0,6],
// monomials of x = u/3 - 1. Max err ~3.5e-4 (<< 5.5e-3 threshold).
constexpr float A0 =  0.0485865f;
constexpr float A1 = -0.1402039f;
constexpr float A2 =  0.2024491f;
constexpr float A3 = -0.2005852f;
constexpr float A4 =  0.1182934f;
constexpr float A5 = -0.0048016f;
constexpr float A6 = -0.0214538f;

template <int NWAVE>
__device__ __forceinline__ float block_reduce(float v, float* smem) {
    #pragma unroll
    for (int off = 32; off > 0; off >>= 1)
        v += __shfl_down(v, off, 64);
    const int lane = threadIdx.x & 63;
    const int wid  = threadIdx.x >> 6;
    if (lane == 0) smem[wid] = v;
    __syncthreads();
    float s = 0.0f;
    if (threadIdx.x == 0) {
        #pragma unroll
        for (int i = 0; i < NWAVE; ++i) s += smem[i];
    }
    return s;  // valid in thread 0 only
}

__global__ __launch_bounds__(BLOCK) void focal_partial(
        const f32x4* __restrict__ x,
        const i32x4* __restrict__ lab4,
        float*       __restrict__ partial) {
    const int p  = blockIdx.x * BLOCK + threadIdx.x;   // pixel-quad index
    const int n  = p >> 16;                            // p / QPP
    const int pq = p & (QPP - 1);

    // Label + per-element valid mask: loaded/computed ONCE for 19 channels.
    const i32x4 l4 = lab4[p];
    int   lab[4];
    float av[4];
    #pragma unroll
    for (int j = 0; j < 4; ++j) {
        lab[j] = l4[j];
        av[j]  = ((lab[j] >= 0) && (lab[j] != IGNORE_INDEX)) ? ALPHA : 0.0f;
    }

    const f32x4* base = x + ((size_t)(n * NC) << 16) + pq;

    float acc = 0.0f;
    #pragma unroll
    for (int c = 0; c < NC; ++c) {
        const f32x4 v = base[(size_t)c << 16];
        #pragma unroll
        for (int j = 0; j < 4; ++j) {
            const float xv = v[j];
            const bool  t  = (lab[j] == c);

            // softplus q(|x|) via degree-6 polynomial, no LDS, no trans.
            const float u  = fminf(fabsf(xv), 6.0f);
            const float xx = fmaf(u, 0.33333333f, -1.0f);
            float sp = A6;
            sp = fmaf(sp, xx, A5);
            sp = fmaf(sp, xx, A4);
            sp = fmaf(sp, xx, A3);
            sp = fmaf(sp, xx, A2);
            sp = fmaf(sp, xx, A1);
            sp = fmaf(sp, xx, A0);

            const float y   = t ? -xv : xv;
            const float d   = y + (t ? 1.0f : 0.0f); // t? 1-x : x
            const float w   = av[j] * d * d;
            const float bce = fmaxf(y, 0.0f) + sp;   // = max(x,0)-x*t+q(|x|)
            acc = fmaf(bce, w, acc);
        }
    }

    __shared__ float smem[BLOCK / 64];
    const float s = block_reduce<BLOCK / 64>(acc, smem);
    if (threadIdx.x == 0) partial[blockIdx.x] = s;
}

__global__ __launch_bounds__(BLOCK2) void focal_finalize(
        const float* __restrict__ partial,
        float*       __restrict__ out) {
    float acc = 0.0f;
    for (int i = threadIdx.x; i < GRID; i += BLOCK2)
        acc += partial[i];
    __shared__ float smem[BLOCK2 / 64];
    const float s = block_reduce<BLOCK2 / 64>(acc, smem);
    if (threadIdx.x == 0) out[0] = s * INV_TOTAL;  // LOSS_WEIGHT == 1.0
}

extern "C" void kernel_launch(void* const* d_in, const int* in_sizes, int n_in,
                              void* d_out, int out_size, void* d_ws, size_t ws_size,
                              hipStream_t stream) {
    const f32x4* cls_score = (const f32x4*)d_in[0];
    const i32x4* lab4      = (const i32x4*)d_in[1];
    float* out     = (float*)d_out;
    float* partial = (float*)d_ws;   // GRID floats

    focal_partial<<<GRID, BLOCK, 0, stream>>>(cls_score, lab4, partial);
    focal_finalize<<<1, BLOCK2, 0, stream>>>(partial, out);
}